// Round 3
// baseline (64.606 us; speedup 1.0000x reference)
//
#include <hip/hip_runtime.h>

// LiftingScheme == plain 3x3 same-padding conv2d (predict/update coeffs cancel
// exactly to w): out[n,o,i,j] = sum_{c,kh,kw} w[o,c,kh,kw]*x[n,c,i+kh-1,j+kw-1]
//
// Round-5: round-4 (prefetch + SGPR discipline) was NEUTRAL vs round-3 ->
// the per-wave instruction stream is not the bottleneck. What r3/r4 share:
// one 16-wave block per CU (stage->compute->reduce fully serialized, whole
// CU stalls at every __syncthreads), 3 block-wide barriers, 32 idle CUs.
// Changes (structure, not instructions):
//  1. 512-thread blocks (8 waves = 2 o-quads x 4 c-chunks), grid (8,28,2) =
//     448 blocks -> 2 co-resident blocks/CU (44 KB LDS each, <=128 VGPR).
//     One block's FMA phase overlaps the other's staging/barrier waits --
//     impossible with a single barrier-synced block per CU.
//  2. Reduction scratch is its OWN LDS region (no xs reuse) -> the middle
//     __syncthreads disappears. 2 barriers total, scope halved to 8 waves.
// Per-wave work identical to round-3 (4 o x 2 cols, 8 ch: 6 ds_read_b64 :
// 72 FMA per channel -> VALU-bound per CU, LDS pipe at ~parity).

namespace {
constexpr int Cc = 32, Hh = 56, Ww = 56, Oo = 64;

constexpr int RSTRIDE = 10;   // floats per lane slot in scratch (8B-aligned, gcd(10,32)=2 -> free 2-way)
constexpr int REGION  = 560;  // 56 lanes * RSTRIDE, per (cchunk-1,oq) partial region

__global__ __launch_bounds__(512, 4)
void lifting_conv_kernel(const float* __restrict__ x,
                         const float* __restrict__ w,
                         float* __restrict__ out)
{
    // x tile: [C][4 padded rows][60 (58 used)] = 7680 floats = 30 KB.
    __shared__ float xs[Cc * 4 * 60];
    // C-partial scratch: 6 regions ((cch-1) x oq) * 560 floats = 13.4 KB.
    __shared__ float rs[6 * REGION];

    const int tid  = threadIdx.x;
    const int og   = blockIdx.x;   // 0..7  -> o0 = 8*og
    const int ip   = blockIdx.y;   // 0..27 -> rows 2*ip, 2*ip+1
    const int n    = blockIdx.z;   // 0..1
    const int i0   = ip * 2;
    const int lane = tid & 63;
    const int wv   = tid >> 6;     // wave id 0..7

    // ---- stage x rows i0-1..i0+2 (zero-padded), cols -1..56 (zero-padded) ----
    // wave wv stages LDS rows {p*8 + wv : p=0..15}; lane = jj (column+1).
    {
        const int col = lane - 1;
        const bool cok = (lane < 58) && ((unsigned)col < (unsigned)Ww);
        float v[16];
        #pragma unroll
        for (int p = 0; p < 16; ++p) {
            const int rowid = p * 8 + wv;      // = c*4 + r, c = rowid>>2
            const int r = rowid & 3;
            const int h = i0 - 1 + r;
            v[p] = 0.0f;
            if (cok && (unsigned)h < (unsigned)Hh)
                v[p] = x[((n * Cc + (rowid >> 2)) * Hh + h) * Ww + col];
        }
        if (lane < 58) {
            #pragma unroll
            for (int p = 0; p < 16; ++p)
                xs[(p * 8 + wv) * 60 + lane] = v[p];
        }
    }
    __syncthreads();

    const int oq   = wv & 1;              // o-quad within the block's 8 o
    const int cch  = wv >> 1;             // c-chunk 0..3 (8 channels each)
    const bool act = lane < 56;           // 56 active lanes per wave
    const int lact = act ? lane : 0;      // inactive lanes compute harmlessly
    const int rsub = (lact >= 28) ? 1 : 0;
    const int cp   = lact - rsub * 28;    // column pair 0..27
    const int col0 = cp * 2;

    // wave-uniform bases -> scalar (SMEM) weight loads, zero LDS spent on weights
    const int o_base = __builtin_amdgcn_readfirstlane(og * 8 + oq * 4);
    const int cbeg   = __builtin_amdgcn_readfirstlane(cch * 8);
    const float* __restrict__ wb = w + ((size_t)o_base * Cc + cbeg) * 9;

    float acc[4][2];
    #pragma unroll
    for (int i = 0; i < 4; ++i) { acc[i][0] = 0.f; acc[i][1] = 0.f; }

    const float* xbase = &xs[cbeg * 240 + rsub * 60 + col0];

    #pragma unroll 2
    for (int cc = 0; cc < 8; ++cc) {
        const float* xr = xbase + cc * 240;
        // 3 rows x 4 cols register window (6x ds_read_b64, 8B-aligned)
        const float2 r0a = *(const float2*)(xr);
        const float2 r0b = *(const float2*)(xr + 2);
        const float2 r1a = *(const float2*)(xr + 60);
        const float2 r1b = *(const float2*)(xr + 62);
        const float2 r2a = *(const float2*)(xr + 120);
        const float2 r2b = *(const float2*)(xr + 122);

        #pragma unroll
        for (int oo = 0; oo < 4; ++oo) {
            const float* wc = wb + (oo * Cc + cc) * 9;  // wave-uniform address
            const float w0 = wc[0], w1 = wc[1], w2 = wc[2],
                        w3 = wc[3], w4 = wc[4], w5 = wc[5],
                        w6 = wc[6], w7 = wc[7], w8 = wc[8];
            acc[oo][0] += w0 * r0a.x + w1 * r0a.y + w2 * r0b.x
                        + w3 * r1a.x + w4 * r1a.y + w5 * r1b.x
                        + w6 * r2a.x + w7 * r2a.y + w8 * r2b.x;
            acc[oo][1] += w0 * r0a.y + w1 * r0b.x + w2 * r0b.y
                        + w3 * r1a.y + w4 * r1b.x + w5 * r1b.y
                        + w6 * r2a.y + w7 * r2b.x + w8 * r2b.y;
        }
    }

    // ---- reduce the 4 C-chunk partials through dedicated LDS scratch ----
    // (no xs reuse -> no barrier needed between compute and partial writes)
    if (cch > 0 && act) {
        float* p = &rs[((cch - 1) * 2 + oq) * REGION + lane * RSTRIDE];
        #pragma unroll
        for (int oo = 0; oo < 4; ++oo)
            *(float2*)(p + oo * 2) = make_float2(acc[oo][0], acc[oo][1]);
    }
    __syncthreads();

    if (cch == 0 && act) {
        #pragma unroll
        for (int pi = 0; pi < 3; ++pi) {
            const float* p = &rs[(pi * 2 + oq) * REGION + lane * RSTRIDE];
            #pragma unroll
            for (int oo = 0; oo < 4; ++oo) {
                const float2 v = *(const float2*)(p + oo * 2);
                acc[oo][0] += v.x;
                acc[oo][1] += v.y;
            }
        }
        const int row = i0 + rsub;
        #pragma unroll
        for (int oo = 0; oo < 4; ++oo) {
            float2 v; v.x = acc[oo][0]; v.y = acc[oo][1];
            *(float2*)(out + ((size_t)(n * Oo + o_base + oo) * Hh + row) * Ww + col0) = v;
        }
    }
}
} // namespace

extern "C" void kernel_launch(void* const* d_in, const int* in_sizes, int n_in,
                              void* d_out, int out_size, void* d_ws, size_t ws_size,
                              hipStream_t stream)
{
    const float* x = (const float*)d_in[0];   // (2,32,56,56) fp32
    const float* w = (const float*)d_in[1];   // (64,32,3,3) fp32
    float* out = (float*)d_out;               // (2,64,56,56) fp32

    dim3 grid(8, 28, 2);  // (o-groups of 8, row-pairs, n) = 448 blocks
    lifting_conv_kernel<<<grid, 512, 0, stream>>>(x, w, out);
}